// Round 2
// baseline (350.529 us; speedup 1.0000x reference)
//
#include <hip/hip_runtime.h>

// SIZE = (D,H,W) = (160,192,160), B=2, C=2.
#define DD 160
#define HH 192
#define WW 160
#define SP (DD * HH * WW)
#define NB 2
#define NC 2

// Tile per block and staged (edge-replicated) region.
// 512 threads/block, 4 samples/thread, channel-split LDS phases.
#define TX 32
#define TY 8
#define TZ 8
#define RXW 40                 // x: [X0-4, X0+35]  supports dx in [-4,4)
#define RYH 15                 // y: [Y0-3, Y0+11]  supports dy in [-3,4)
#define RZD 15                 // z: [Z0-3, Z0+11]  supports dz in [-3,4)
#define REGC (RZD * RYH * RXW) // 9000 voxels; LDS = 4B*9000 = 36.0 KB -> 4 blocks/CU
#define NCHUNK (REGC / 4)      // 2250 4-voxel chunks
#define NITER 5                // ceil(2250/512)

#define NTX 5
#define NTY 24
#define NTZ 20
#define NTILES (NTX * NTY * NTZ * NB)   // 4800 blocks
#define PER_XCD (NTILES / 8)

typedef float v2f __attribute__((ext_vector_type(2)));
typedef float v4f __attribute__((ext_vector_type(4)));

__device__ __forceinline__ v4f ld4_nt(const float* p) {
    return __builtin_nontemporal_load(reinterpret_cast<const v4f*>(p));
}
__device__ __forceinline__ void st4_nt(float* p, v4f v) {
    __builtin_nontemporal_store(v, reinterpret_cast<v4f*>(p));
}
__device__ __forceinline__ v2f ld2g(const float* p) {
    return *reinterpret_cast<const v2f*>(p);
}

// Rare fallback: displacement outside staged halo — full global trilinear,
// both channels at once.
__device__ __forceinline__ void sample_global(
    const float* __restrict__ s0, const float* __restrict__ s1,
    int x, int y, int z, float dx, float dy, float dz,
    float& a0, float& a1)
{
    float sx = (float)x + dx, sy = (float)y + dy, sz = (float)z + dz;
    float xf = floorf(sx), yf = floorf(sy), zf = floorf(sz);
    float fx = sx - xf, fy = sy - yf, fz = sz - zf;
    int x0 = (int)xf, y0 = (int)yf, z0 = (int)zf;
    int x1 = x0 + 1, y1 = y0 + 1, z1 = z0 + 1;

    float wx0 = (x0 >= 0 && x0 < WW) ? (1.0f - fx) : 0.0f;
    float wx1 = (x1 >= 0 && x1 < WW) ? fx : 0.0f;
    float wy0 = (y0 >= 0 && y0 < HH) ? (1.0f - fy) : 0.0f;
    float wy1 = (y1 >= 0 && y1 < HH) ? fy : 0.0f;
    float wz0 = (z0 >= 0 && z0 < DD) ? (1.0f - fz) : 0.0f;
    float wz1 = (z1 >= 0 && z1 < DD) ? fz : 0.0f;

    int p  = min(max(x0, 0), WW - 2);
    int i0 = min(max(x0, 0), WW - 1) - p;
    int i1 = min(max(x1, 0), WW - 1) - p;
    int cy0 = min(max(y0, 0), HH - 1), cy1 = min(max(y1, 0), HH - 1);
    int cz0 = min(max(z0, 0), DD - 1), cz1 = min(max(z1, 0), DD - 1);

    int o00 = (cz0 * HH + cy0) * WW + p;
    int o01 = (cz0 * HH + cy1) * WW + p;
    int o10 = (cz1 * HH + cy0) * WW + p;
    int o11 = (cz1 * HH + cy1) * WW + p;

    float w00 = wz0 * wy0, w01 = wz0 * wy1, w10 = wz1 * wy0, w11 = wz1 * wy1;

    v2f c0_00 = ld2g(s0 + o00); v2f c1_00 = ld2g(s1 + o00);
    v2f c0_01 = ld2g(s0 + o01); v2f c1_01 = ld2g(s1 + o01);
    v2f c0_10 = ld2g(s0 + o10); v2f c1_10 = ld2g(s1 + o10);
    v2f c0_11 = ld2g(s0 + o11); v2f c1_11 = ld2g(s1 + o11);

    #define PICK(v, i) ((i) ? (v).y : (v).x)
    float r0, r1;
    r0  = w00 * (wx0 * PICK(c0_00, i0) + wx1 * PICK(c0_00, i1));
    r1  = w00 * (wx0 * PICK(c1_00, i0) + wx1 * PICK(c1_00, i1));
    r0 += w01 * (wx0 * PICK(c0_01, i0) + wx1 * PICK(c0_01, i1));
    r1 += w01 * (wx0 * PICK(c1_01, i0) + wx1 * PICK(c1_01, i1));
    r0 += w10 * (wx0 * PICK(c0_10, i0) + wx1 * PICK(c0_10, i1));
    r1 += w10 * (wx0 * PICK(c1_10, i0) + wx1 * PICK(c1_10, i1));
    r0 += w11 * (wx0 * PICK(c0_11, i0) + wx1 * PICK(c0_11, i1));
    r1 += w11 * (wx0 * PICK(c1_11, i0) + wx1 * PICK(c1_11, i1));
    #undef PICK
    a0 = r0; a1 = r1;
}

// Issue the staged-region global loads for one channel (base cb) into regs.
__device__ __forceinline__ void stage_issue(
    const float* __restrict__ cb, int X0, int Y0, int Z0, int tid,
    v4f* v, int* ad)
{
    #pragma unroll
    for (int i = 0; i < NITER; ++i) {
        int c = tid + i * 512;
        if (i < NITER - 1 || c < NCHUNK) {
            int lz  = c / 150;  int r2 = c - lz * 150;   // 150 = RYH*RXW/4
            int ly  = r2 / 10;  int lxc = r2 - ly * 10;  // 10 = RXW/4
            int mz = min(max(Z0 - 3 + lz, 0), DD - 1);
            int my = min(max(Y0 - 3 + ly, 0), HH - 1);
            int mx = X0 - 4 + lxc * 4;
            const float* p = cb + (mz * HH + my) * WW;
            v4f A;
            if (mx >= 0 && mx <= WW - 4) {
                A = *reinterpret_cast<const v4f*>(p + mx);
            } else {   // volume x-edge chunks only
                int m0 = min(max(mx,     0), WW - 1);
                int m1 = min(max(mx + 1, 0), WW - 1);
                int m2 = min(max(mx + 2, 0), WW - 1);
                int m3 = min(max(mx + 3, 0), WW - 1);
                A.x = p[m0]; A.y = p[m1]; A.z = p[m2]; A.w = p[m3];
            }
            v[i] = A;
            ad[i] = (lz * RYH + ly) * RXW + lxc * 4;   // 16B-aligned float index
        } else {
            ad[i] = -1;
        }
    }
}

__device__ __forceinline__ void stage_write(float* sbuf, const v4f* v, const int* ad)
{
    #pragma unroll
    for (int i = 0; i < NITER; ++i) {
        if (ad[i] >= 0) {
            *reinterpret_cast<v4f*>(&sbuf[ad[i]]) = v[i];
        }
    }
}

// Trilinear sample of the single-channel staged region.
__device__ __forceinline__ float sample_lds(
    const float* __restrict__ sbuf,
    float lx, float ly, float lz, int rx0, int ry0, int rz0)
{
    float xf = floorf(lx), yf = floorf(ly), zf = floorf(lz);
    float fx = lx - xf, fy = ly - yf, fz = lz - zf;
    int ix = (int)xf, iy = (int)yf, iz = (int)zf;

    // Zero-weight masks vs volume bounds (values come edge-replicated from
    // LDS — no index clamping needed, staged data already clamped).
    int vx0 = ix + rx0, vy0 = iy + ry0, vz0 = iz + rz0;
    float wx0 = (vx0 >= 0  && vx0 < WW)     ? (1.0f - fx) : 0.0f;
    float wx1 = (vx0 >= -1 && vx0 < WW - 1) ? fx          : 0.0f;
    float wy0 = (vy0 >= 0  && vy0 < HH)     ? (1.0f - fy) : 0.0f;
    float wy1 = (vy0 >= -1 && vy0 < HH - 1) ? fy          : 0.0f;
    float wz0 = (vz0 >= 0  && vz0 < DD)     ? (1.0f - fz) : 0.0f;
    float wz1 = (vz0 >= -1 && vz0 < DD - 1) ? fz          : 0.0f;

    const float* pB = sbuf + (iz * RYH + iy) * RXW + ix;
    // Adjacent x0/x1 pairs -> ds_read2_b32.
    float A00 = pB[0],        B00 = pB[1];
    float A01 = pB[RXW],      B01 = pB[RXW + 1];
    const float* pC = pB + RYH * RXW;
    float A10 = pC[0],        B10 = pC[1];
    float A11 = pC[RXW],      B11 = pC[RXW + 1];

    float c00 = wx0 * A00 + wx1 * B00;
    float c01 = wx0 * A01 + wx1 * B01;
    float c10 = wx0 * A10 + wx1 * B10;
    float c11 = wx0 * A11 + wx1 * B11;
    float m0  = wy0 * c00 + wy1 * c01;
    float m1  = wy0 * c10 + wy1 * c11;
    return wz0 * m0 + wz1 * m1;
}

__global__ __launch_bounds__(512, 8) void st_warp_kernel(
    const float* __restrict__ src,   // [B, C, D, H, W]
    const float* __restrict__ flow,  // [B, 3, D, H, W]
    float* __restrict__ out)         // [B, C, D, H, W]
{
    // Single-channel staged region, reused across two phases.
    __shared__ float sbuf[REGC];   // 36,000 B -> 4 blocks/CU (32 waves)

    int u   = blockIdx.x;
    int tl  = (u & 7) * PER_XCD + (u >> 3);   // XCD-contiguous tile ranges
    int tx  = tl % NTX;  int t2 = tl / NTX;
    int ty  = t2 % NTY;  int t3 = t2 / NTY;
    int tz  = t3 % NTZ;  int b  = t3 / NTZ;
    int X0 = tx * TX, Y0 = ty * TY, Z0 = tz * TZ;
    int tid = threadIdx.x;

    const float* sb = src + b * NC * SP;   // channel 0 base (c1 at +SP)

    // ---- Phase 1 stage: channel 0 ----
    v4f vs[NITER];
    int  ad[NITER];
    stage_issue(sb, X0, Y0, Z0, tid, vs, ad);

    // ---- Flow loads (in flight across staging) ----
    int rr = tid >> 3;
    int xi = (tid & 7) << 2;
    int yl = rr & 7, zl = rr >> 3;
    int y = Y0 + yl, z = Z0 + zl, x = X0 + xi;
    int fo = b * 3 * SP + (z * HH + y) * WW + x;
    v4f dxv = ld4_nt(flow + fo);
    v4f dyv = ld4_nt(flow + fo + SP);
    v4f dzv = ld4_nt(flow + fo + 2 * SP);

    stage_write(sbuf, vs, ad);
    __syncthreads();

    // ---- Phase 1 compute: channel 0 (fallback fills both channels) ----
    const int rx0 = X0 - 4, ry0 = Y0 - 3, rz0 = Z0 - 3;
    float a0[4], a1[4];
    #pragma unroll
    for (int j = 0; j < 4; ++j) {
        float dx = dxv[j], dy = dyv[j], dz = dzv[j];
        bool inH = (dx >= -4.0f) & (dx < 4.0f) &
                   (dy >= -3.0f) & (dy < 4.0f) &
                   (dz >= -3.0f) & (dz < 4.0f);
        if (inH) {
            float lx = (float)(xi + j + 4) + dx;
            float ly = (float)(yl + 3) + dy;
            float lz = (float)(zl + 3) + dz;
            a0[j] = sample_lds(sbuf, lx, ly, lz, rx0, ry0, rz0);
        } else {
            // ~0.3% of samples: outside staged halo (or NaN).
            sample_global(sb, sb + SP, x + j, y, z, dx, dy, dz, a0[j], a1[j]);
        }
    }
    __syncthreads();   // all waves done reading c0 from LDS

    // ---- Phase 2 stage: channel 1 into the same buffer ----
    stage_issue(sb + SP, X0, Y0, Z0, tid, vs, ad);
    stage_write(sbuf, vs, ad);
    __syncthreads();

    // ---- Phase 2 compute: channel 1 (weights recomputed from live flow regs) ----
    #pragma unroll
    for (int j = 0; j < 4; ++j) {
        float dx = dxv[j], dy = dyv[j], dz = dzv[j];
        bool inH = (dx >= -4.0f) & (dx < 4.0f) &
                   (dy >= -3.0f) & (dy < 4.0f) &
                   (dz >= -3.0f) & (dz < 4.0f);
        if (inH) {
            float lx = (float)(xi + j + 4) + dx;
            float ly = (float)(yl + 3) + dy;
            float lz = (float)(zl + 3) + dz;
            a1[j] = sample_lds(sbuf, lx, ly, lz, rx0, ry0, rz0);
        }
        // else: a1[j] already set by the phase-1 fallback.
    }

    int oo = b * NC * SP + (z * HH + y) * WW + x;
    v4f o0 = {a0[0], a0[1], a0[2], a0[3]};
    v4f o1 = {a1[0], a1[1], a1[2], a1[3]};
    st4_nt(out + oo, o0);
    st4_nt(out + oo + SP, o1);
}

extern "C" void kernel_launch(void* const* d_in, const int* in_sizes, int n_in,
                              void* d_out, int out_size, void* d_ws, size_t ws_size,
                              hipStream_t stream) {
    const float* src  = (const float*)d_in[0];
    const float* flow = (const float*)d_in[1];
    float* out = (float*)d_out;

    st_warp_kernel<<<NTILES, 512, 0, stream>>>(src, flow, out);
}

// Round 3
// 319.231 us; speedup vs baseline: 1.0980x; 1.0980x over previous
//
#include <hip/hip_runtime.h>

// SIZE = (D,H,W) = (160,192,160), B=2, C=2.
#define DD 160
#define HH 192
#define WW 160
#define SP (DD * HH * WW)
#define NB 2
#define NC 2

// Tile per block and staged (edge-replicated) region.
// 512 threads/block, 4 samples/thread, channel-split LDS phases,
// staging via global_load_lds (no VGPR round trip).
#define TX 32
#define TY 8
#define TZ 8
#define RXW 40                 // x: [X0-4, X0+35]  supports dx in [-4,4)
#define RYH 15                 // y: [Y0-3, Y0+11]  supports dy in [-3,4)
#define RZD 15                 // z: [Z0-3, Z0+11]  supports dz in [-3,4)
#define REGC (RZD * RYH * RXW) // 9000 voxels; LDS = 4B*9000 = 36.0 KB -> 4 blocks/CU
#define NCHUNK (REGC / 4)      // 2250 4-voxel chunks
#define NITER 5                // ceil(2250/512)

#define NTX 5
#define NTY 24
#define NTZ 20
#define NTILES (NTX * NTY * NTZ * NB)   // 4800 blocks
#define PER_XCD (NTILES / 8)

typedef float v2f __attribute__((ext_vector_type(2)));
typedef float v4f __attribute__((ext_vector_type(4)));

typedef const void __attribute__((address_space(1)))* gas_ptr;
typedef void __attribute__((address_space(3)))* las_ptr;

__device__ __forceinline__ v4f ld4_nt(const float* p) {
    return __builtin_nontemporal_load(reinterpret_cast<const v4f*>(p));
}
__device__ __forceinline__ void st4_nt(float* p, v4f v) {
    __builtin_nontemporal_store(v, reinterpret_cast<v4f*>(p));
}
__device__ __forceinline__ v2f ld2g(const float* p) {
    return *reinterpret_cast<const v2f*>(p);
}

// Rare fallback: displacement outside staged halo — full global trilinear,
// both channels at once.
__device__ __forceinline__ void sample_global(
    const float* __restrict__ s0, const float* __restrict__ s1,
    int x, int y, int z, float dx, float dy, float dz,
    float& a0, float& a1)
{
    float sx = (float)x + dx, sy = (float)y + dy, sz = (float)z + dz;
    float xf = floorf(sx), yf = floorf(sy), zf = floorf(sz);
    float fx = sx - xf, fy = sy - yf, fz = sz - zf;
    int x0 = (int)xf, y0 = (int)yf, z0 = (int)zf;
    int x1 = x0 + 1, y1 = y0 + 1, z1 = z0 + 1;

    float wx0 = (x0 >= 0 && x0 < WW) ? (1.0f - fx) : 0.0f;
    float wx1 = (x1 >= 0 && x1 < WW) ? fx : 0.0f;
    float wy0 = (y0 >= 0 && y0 < HH) ? (1.0f - fy) : 0.0f;
    float wy1 = (y1 >= 0 && y1 < HH) ? fy : 0.0f;
    float wz0 = (z0 >= 0 && z0 < DD) ? (1.0f - fz) : 0.0f;
    float wz1 = (z1 >= 0 && z1 < DD) ? fz : 0.0f;

    int p  = min(max(x0, 0), WW - 2);
    int i0 = min(max(x0, 0), WW - 1) - p;
    int i1 = min(max(x1, 0), WW - 1) - p;
    int cy0 = min(max(y0, 0), HH - 1), cy1 = min(max(y1, 0), HH - 1);
    int cz0 = min(max(z0, 0), DD - 1), cz1 = min(max(z1, 0), DD - 1);

    int o00 = (cz0 * HH + cy0) * WW + p;
    int o01 = (cz0 * HH + cy1) * WW + p;
    int o10 = (cz1 * HH + cy0) * WW + p;
    int o11 = (cz1 * HH + cy1) * WW + p;

    float w00 = wz0 * wy0, w01 = wz0 * wy1, w10 = wz1 * wy0, w11 = wz1 * wy1;

    v2f c0_00 = ld2g(s0 + o00); v2f c1_00 = ld2g(s1 + o00);
    v2f c0_01 = ld2g(s0 + o01); v2f c1_01 = ld2g(s1 + o01);
    v2f c0_10 = ld2g(s0 + o10); v2f c1_10 = ld2g(s1 + o10);
    v2f c0_11 = ld2g(s0 + o11); v2f c1_11 = ld2g(s1 + o11);

    #define PICK(v, i) ((i) ? (v).y : (v).x)
    float r0, r1;
    r0  = w00 * (wx0 * PICK(c0_00, i0) + wx1 * PICK(c0_00, i1));
    r1  = w00 * (wx0 * PICK(c1_00, i0) + wx1 * PICK(c1_00, i1));
    r0 += w01 * (wx0 * PICK(c0_01, i0) + wx1 * PICK(c0_01, i1));
    r1 += w01 * (wx0 * PICK(c1_01, i0) + wx1 * PICK(c1_01, i1));
    r0 += w10 * (wx0 * PICK(c0_10, i0) + wx1 * PICK(c0_10, i1));
    r1 += w10 * (wx0 * PICK(c1_10, i0) + wx1 * PICK(c1_10, i1));
    r0 += w11 * (wx0 * PICK(c0_11, i0) + wx1 * PICK(c0_11, i1));
    r1 += w11 * (wx0 * PICK(c1_11, i0) + wx1 * PICK(c1_11, i1));
    #undef PICK
    a0 = r0; a1 = r1;
}

// Stage one channel into LDS via direct global->LDS DMA.
// Chunk c lands at sbuf[4c] (layout identity: region idx of chunk c == 4c),
// so within a wave the LDS destination is base + lane*16 — exactly the
// global_load_lds constraint. Edge chunks load a clamped-base (wrong)
// 16B; fix_edge repairs them after the barrier.
__device__ __forceinline__ void stage_channel(
    const float* __restrict__ cb, int X0, int Y0, int Z0, int tid, float* sbuf)
{
    #pragma unroll
    for (int i = 0; i < NITER; ++i) {
        int c = tid + i * 512;
        if (i < NITER - 1 || c < NCHUNK) {
            int lz  = c / 150;  int r2 = c - lz * 150;   // 150 = RYH*RXW/4
            int ly  = r2 / 10;  int lxc = r2 - ly * 10;  // 10 = RXW/4
            int mz = min(max(Z0 - 3 + lz, 0), DD - 1);
            int my = min(max(Y0 - 3 + ly, 0), HH - 1);
            int mx = min(max(X0 - 4 + lxc * 4, 0), WW - 4);  // 16B-aligned
            const float* g = cb + (mz * HH + my) * WW + mx;
            __builtin_amdgcn_global_load_lds(
                (gas_ptr)g, (las_ptr)(sbuf + 4 * c), 16, 0, 0);
        }
    }
}

// Repair edge-replicated chunks (only blocks at volume x-edges).
// Edge chunks are FULLY out of range by construction (X0 % 32 == 0), so all
// four elements equal a single clamped voxel.
__device__ __forceinline__ void fix_edge(float* sbuf, int tid, bool left)
{
    if (tid < RZD * RYH) {   // 225 edge chunks
        int lz = tid / RYH, ly = tid - lz * RYH;
        int base = (lz * RYH + ly) * RXW + (left ? 0 : RXW - 4);
        if (left) {          // desired: all = volume x=0 -> loaded elem 0
            float v = sbuf[base];
            sbuf[base + 1] = v; sbuf[base + 2] = v; sbuf[base + 3] = v;
        } else {             // desired: all = volume x=159 -> loaded elem 3
            float v = sbuf[base + 3];
            sbuf[base] = v; sbuf[base + 1] = v; sbuf[base + 2] = v;
        }
    }
}

// Trilinear sample of the single-channel staged region.
__device__ __forceinline__ float sample_lds(
    const float* __restrict__ sbuf,
    float lx, float ly, float lz, int rx0, int ry0, int rz0)
{
    float xf = floorf(lx), yf = floorf(ly), zf = floorf(lz);
    float fx = lx - xf, fy = ly - yf, fz = lz - zf;
    int ix = (int)xf, iy = (int)yf, iz = (int)zf;

    // Zero-weight masks vs volume bounds (values come edge-replicated from
    // LDS — no index clamping needed, staged data already clamped).
    int vx0 = ix + rx0, vy0 = iy + ry0, vz0 = iz + rz0;
    float wx0 = (vx0 >= 0  && vx0 < WW)     ? (1.0f - fx) : 0.0f;
    float wx1 = (vx0 >= -1 && vx0 < WW - 1) ? fx          : 0.0f;
    float wy0 = (vy0 >= 0  && vy0 < HH)     ? (1.0f - fy) : 0.0f;
    float wy1 = (vy0 >= -1 && vy0 < HH - 1) ? fy          : 0.0f;
    float wz0 = (vz0 >= 0  && vz0 < DD)     ? (1.0f - fz) : 0.0f;
    float wz1 = (vz0 >= -1 && vz0 < DD - 1) ? fz          : 0.0f;

    const float* pB = sbuf + (iz * RYH + iy) * RXW + ix;
    // Adjacent x0/x1 pairs -> ds_read2_b32.
    float A00 = pB[0],        B00 = pB[1];
    float A01 = pB[RXW],      B01 = pB[RXW + 1];
    const float* pC = pB + RYH * RXW;
    float A10 = pC[0],        B10 = pC[1];
    float A11 = pC[RXW],      B11 = pC[RXW + 1];

    float c00 = wx0 * A00 + wx1 * B00;
    float c01 = wx0 * A01 + wx1 * B01;
    float c10 = wx0 * A10 + wx1 * B10;
    float c11 = wx0 * A11 + wx1 * B11;
    float m0  = wy0 * c00 + wy1 * c01;
    float m1  = wy0 * c10 + wy1 * c11;
    return wz0 * m0 + wz1 * m1;
}

__global__ __launch_bounds__(512, 8) void st_warp_kernel(
    const float* __restrict__ src,   // [B, C, D, H, W]
    const float* __restrict__ flow,  // [B, 3, D, H, W]
    float* __restrict__ out)         // [B, C, D, H, W]
{
    // Single-channel staged region, reused across two phases.
    __shared__ float sbuf[REGC];   // 36,000 B -> 4 blocks/CU (32 waves)

    int u   = blockIdx.x;
    int tl  = (u & 7) * PER_XCD + (u >> 3);   // XCD-contiguous tile ranges
    int tx  = tl % NTX;  int t2 = tl / NTX;
    int ty  = t2 % NTY;  int t3 = t2 / NTY;
    int tz  = t3 % NTZ;  int b  = t3 / NTZ;
    int X0 = tx * TX, Y0 = ty * TY, Z0 = tz * TZ;
    int tid = threadIdx.x;

    const bool edge = (tx == 0) | (tx == NTX - 1);   // block-uniform
    const bool left = (tx == 0);

    const float* sb = src + b * NC * SP;   // channel 0 base (c1 at +SP)

    // ---- Phase 1 stage: channel 0 (direct global->LDS, no VGPRs) ----
    stage_channel(sb, X0, Y0, Z0, tid, sbuf);

    // ---- Flow loads (in flight across staging drain) ----
    int rr = tid >> 3;
    int xi = (tid & 7) << 2;
    int yl = rr & 7, zl = rr >> 3;
    int y = Y0 + yl, z = Z0 + zl, x = X0 + xi;
    int fo = b * 3 * SP + (z * HH + y) * WW + x;
    v4f dxv = ld4_nt(flow + fo);
    v4f dyv = ld4_nt(flow + fo + SP);
    v4f dzv = ld4_nt(flow + fo + 2 * SP);

    __syncthreads();                 // drains vmcnt: LDS staged
    if (edge) {                      // block-uniform branch
        fix_edge(sbuf, tid, left);
        __syncthreads();
    }

    // ---- Phase 1 compute: channel 0 (fallback fills both channels) ----
    const int rx0 = X0 - 4, ry0 = Y0 - 3, rz0 = Z0 - 3;
    float a0[4], a1[4];
    #pragma unroll
    for (int j = 0; j < 4; ++j) {
        float dx = dxv[j], dy = dyv[j], dz = dzv[j];
        bool inH = (dx >= -4.0f) & (dx < 4.0f) &
                   (dy >= -3.0f) & (dy < 4.0f) &
                   (dz >= -3.0f) & (dz < 4.0f);
        if (inH) {
            float lx = (float)(xi + j + 4) + dx;
            float ly = (float)(yl + 3) + dy;
            float lz = (float)(zl + 3) + dz;
            a0[j] = sample_lds(sbuf, lx, ly, lz, rx0, ry0, rz0);
        } else {
            // ~0.3% of samples: outside staged halo (or NaN).
            sample_global(sb, sb + SP, x + j, y, z, dx, dy, dz, a0[j], a1[j]);
        }
    }
    __syncthreads();   // all waves done reading c0 from LDS

    // ---- Phase 2 stage: channel 1 into the same buffer ----
    stage_channel(sb + SP, X0, Y0, Z0, tid, sbuf);
    __syncthreads();
    if (edge) {
        fix_edge(sbuf, tid, left);
        __syncthreads();
    }

    // ---- Phase 2 compute: channel 1 (weights recomputed from live flow regs) ----
    #pragma unroll
    for (int j = 0; j < 4; ++j) {
        float dx = dxv[j], dy = dyv[j], dz = dzv[j];
        bool inH = (dx >= -4.0f) & (dx < 4.0f) &
                   (dy >= -3.0f) & (dy < 4.0f) &
                   (dz >= -3.0f) & (dz < 4.0f);
        if (inH) {
            float lx = (float)(xi + j + 4) + dx;
            float ly = (float)(yl + 3) + dy;
            float lz = (float)(zl + 3) + dz;
            a1[j] = sample_lds(sbuf, lx, ly, lz, rx0, ry0, rz0);
        }
        // else: a1[j] already set by the phase-1 fallback.
    }

    int oo = b * NC * SP + (z * HH + y) * WW + x;
    v4f o0 = {a0[0], a0[1], a0[2], a0[3]};
    v4f o1 = {a1[0], a1[1], a1[2], a1[3]};
    st4_nt(out + oo, o0);
    st4_nt(out + oo + SP, o1);
}

extern "C" void kernel_launch(void* const* d_in, const int* in_sizes, int n_in,
                              void* d_out, int out_size, void* d_ws, size_t ws_size,
                              hipStream_t stream) {
    const float* src  = (const float*)d_in[0];
    const float* flow = (const float*)d_in[1];
    float* out = (float*)d_out;

    st_warp_kernel<<<NTILES, 512, 0, stream>>>(src, flow, out);
}

// Round 4
// 283.255 us; speedup vs baseline: 1.2375x; 1.1270x over previous
//
#include <hip/hip_runtime.h>

// SIZE = (D,H,W) = (160,192,160), B=2, C=2.
#define DD 160
#define HH 192
#define WW 160
#define SP (DD * HH * WW)
#define NB 2
#define NC 2

// Tile per block and staged (edge-replicated) region.
// 512 threads/block, 4 samples/thread, channel-split LDS phases,
// staging via global_load_lds (no VGPR round trip).
// Phases are fully independent (own flow load, own fallback, own store)
// so no float state lives across the phase boundary -> no spill at 64 VGPR.
#define TX 32
#define TY 8
#define TZ 8
#define RXW 40                 // x: [X0-4, X0+35]  supports dx in [-4,4)
#define RYH 15                 // y: [Y0-3, Y0+11]  supports dy in [-3,4)
#define RZD 15                 // z: [Z0-3, Z0+11]  supports dz in [-3,4)
#define REGC (RZD * RYH * RXW) // 9000 voxels; LDS = 4B*9000 = 36.0 KB -> 4 blocks/CU
#define NCHUNK (REGC / 4)      // 2250 4-voxel chunks
#define NITER 5                // ceil(2250/512)

#define NTX 5
#define NTY 24
#define NTZ 20
#define NTILES (NTX * NTY * NTZ * NB)   // 4800 blocks
#define PER_XCD (NTILES / 8)

typedef float v2f __attribute__((ext_vector_type(2)));
typedef float v4f __attribute__((ext_vector_type(4)));

typedef const void __attribute__((address_space(1)))* gas_ptr;
typedef void __attribute__((address_space(3)))* las_ptr;

__device__ __forceinline__ void st4_nt(float* p, v4f v) {
    __builtin_nontemporal_store(v, reinterpret_cast<v4f*>(p));
}
__device__ __forceinline__ v2f ld2g(const float* p) {
    return *reinterpret_cast<const v2f*>(p);
}

// Rare fallback: displacement outside staged halo — full global trilinear,
// single channel.
__device__ __forceinline__ float sample_global1(
    const float* __restrict__ s,
    int x, int y, int z, float dx, float dy, float dz)
{
    float sx = (float)x + dx, sy = (float)y + dy, sz = (float)z + dz;
    float xf = floorf(sx), yf = floorf(sy), zf = floorf(sz);
    float fx = sx - xf, fy = sy - yf, fz = sz - zf;
    int x0 = (int)xf, y0 = (int)yf, z0 = (int)zf;
    int x1 = x0 + 1, y1 = y0 + 1, z1 = z0 + 1;

    float wx0 = (x0 >= 0 && x0 < WW) ? (1.0f - fx) : 0.0f;
    float wx1 = (x1 >= 0 && x1 < WW) ? fx : 0.0f;
    float wy0 = (y0 >= 0 && y0 < HH) ? (1.0f - fy) : 0.0f;
    float wy1 = (y1 >= 0 && y1 < HH) ? fy : 0.0f;
    float wz0 = (z0 >= 0 && z0 < DD) ? (1.0f - fz) : 0.0f;
    float wz1 = (z1 >= 0 && z1 < DD) ? fz : 0.0f;

    int p  = min(max(x0, 0), WW - 2);
    int i0 = min(max(x0, 0), WW - 1) - p;
    int i1 = min(max(x1, 0), WW - 1) - p;
    int cy0 = min(max(y0, 0), HH - 1), cy1 = min(max(y1, 0), HH - 1);
    int cz0 = min(max(z0, 0), DD - 1), cz1 = min(max(z1, 0), DD - 1);

    int o00 = (cz0 * HH + cy0) * WW + p;
    int o01 = (cz0 * HH + cy1) * WW + p;
    int o10 = (cz1 * HH + cy0) * WW + p;
    int o11 = (cz1 * HH + cy1) * WW + p;

    v2f c00 = ld2g(s + o00);
    v2f c01 = ld2g(s + o01);
    v2f c10 = ld2g(s + o10);
    v2f c11 = ld2g(s + o11);

    #define PICK(v, i) ((i) ? (v).y : (v).x)
    float r;
    r  = (wz0 * wy0) * (wx0 * PICK(c00, i0) + wx1 * PICK(c00, i1));
    r += (wz0 * wy1) * (wx0 * PICK(c01, i0) + wx1 * PICK(c01, i1));
    r += (wz1 * wy0) * (wx0 * PICK(c10, i0) + wx1 * PICK(c10, i1));
    r += (wz1 * wy1) * (wx0 * PICK(c11, i0) + wx1 * PICK(c11, i1));
    #undef PICK
    return r;
}

// Stage one channel into LDS via direct global->LDS DMA.
// Chunk c lands at sbuf[4c] (layout identity: region idx of chunk c == 4c),
// so within a wave the LDS destination is base + lane*16 — exactly the
// global_load_lds constraint. Edge chunks load a clamped-base (wrong)
// 16B; fix_edge repairs them after the barrier.
__device__ __forceinline__ void stage_channel(
    const float* __restrict__ cb, int X0, int Y0, int Z0, int tid, float* sbuf)
{
    #pragma unroll
    for (int i = 0; i < NITER; ++i) {
        int c = tid + i * 512;
        if (i < NITER - 1 || c < NCHUNK) {
            int lz  = c / 150;  int r2 = c - lz * 150;   // 150 = RYH*RXW/4
            int ly  = r2 / 10;  int lxc = r2 - ly * 10;  // 10 = RXW/4
            int mz = min(max(Z0 - 3 + lz, 0), DD - 1);
            int my = min(max(Y0 - 3 + ly, 0), HH - 1);
            int mx = min(max(X0 - 4 + lxc * 4, 0), WW - 4);  // 16B-aligned
            const float* g = cb + (mz * HH + my) * WW + mx;
            __builtin_amdgcn_global_load_lds(
                (gas_ptr)g, (las_ptr)(sbuf + 4 * c), 16, 0, 0);
        }
    }
}

// Repair edge-replicated chunks (only blocks at volume x-edges).
// Edge chunks are FULLY out of range by construction (X0 % 32 == 0), so all
// four elements equal a single clamped voxel.
__device__ __forceinline__ void fix_edge(float* sbuf, int tid, bool left)
{
    if (tid < RZD * RYH) {   // 225 edge chunks
        int lz = tid / RYH, ly = tid - lz * RYH;
        int base = (lz * RYH + ly) * RXW + (left ? 0 : RXW - 4);
        if (left) {          // desired: all = volume x=0 -> loaded elem 0
            float v = sbuf[base];
            sbuf[base + 1] = v; sbuf[base + 2] = v; sbuf[base + 3] = v;
        } else {             // desired: all = volume x=159 -> loaded elem 3
            float v = sbuf[base + 3];
            sbuf[base] = v; sbuf[base + 1] = v; sbuf[base + 2] = v;
        }
    }
}

// Trilinear sample of the single-channel staged region.
__device__ __forceinline__ float sample_lds(
    const float* __restrict__ sbuf,
    float lx, float ly, float lz, int rx0, int ry0, int rz0)
{
    float xf = floorf(lx), yf = floorf(ly), zf = floorf(lz);
    float fx = lx - xf, fy = ly - yf, fz = lz - zf;
    int ix = (int)xf, iy = (int)yf, iz = (int)zf;

    // Zero-weight masks vs volume bounds (values come edge-replicated from
    // LDS — no index clamping needed, staged data already clamped).
    int vx0 = ix + rx0, vy0 = iy + ry0, vz0 = iz + rz0;
    float wx0 = (vx0 >= 0  && vx0 < WW)     ? (1.0f - fx) : 0.0f;
    float wx1 = (vx0 >= -1 && vx0 < WW - 1) ? fx          : 0.0f;
    float wy0 = (vy0 >= 0  && vy0 < HH)     ? (1.0f - fy) : 0.0f;
    float wy1 = (vy0 >= -1 && vy0 < HH - 1) ? fy          : 0.0f;
    float wz0 = (vz0 >= 0  && vz0 < DD)     ? (1.0f - fz) : 0.0f;
    float wz1 = (vz0 >= -1 && vz0 < DD - 1) ? fz          : 0.0f;

    const float* pB = sbuf + (iz * RYH + iy) * RXW + ix;
    // Adjacent x0/x1 pairs -> ds_read2_b32.
    float A00 = pB[0],        B00 = pB[1];
    float A01 = pB[RXW],      B01 = pB[RXW + 1];
    const float* pC = pB + RYH * RXW;
    float A10 = pC[0],        B10 = pC[1];
    float A11 = pC[RXW],      B11 = pC[RXW + 1];

    float c00 = wx0 * A00 + wx1 * B00;
    float c01 = wx0 * A01 + wx1 * B01;
    float c10 = wx0 * A10 + wx1 * B10;
    float c11 = wx0 * A11 + wx1 * B11;
    float m0  = wy0 * c00 + wy1 * c01;
    float m1  = wy0 * c10 + wy1 * c11;
    return wz0 * m0 + wz1 * m1;
}

__global__ __launch_bounds__(512, 8) void st_warp_kernel(
    const float* __restrict__ src,   // [B, C, D, H, W]
    const float* __restrict__ flow,  // [B, 3, D, H, W]
    float* __restrict__ out)         // [B, C, D, H, W]
{
    // Single-channel staged region, reused across two phases.
    __shared__ float sbuf[REGC];   // 36,000 B -> 4 blocks/CU (32 waves)

    int u   = blockIdx.x;
    int tl  = (u & 7) * PER_XCD + (u >> 3);   // XCD-contiguous tile ranges
    int tx  = tl % NTX;  int t2 = tl / NTX;
    int ty  = t2 % NTY;  int t3 = t2 / NTY;
    int tz  = t3 % NTZ;  int b  = t3 / NTZ;
    int X0 = tx * TX, Y0 = ty * TY, Z0 = tz * TZ;
    int tid = threadIdx.x;

    const bool edge = (tx == 0) | (tx == NTX - 1);   // block-uniform
    const bool left = (tx == 0);

    const float* sb = src + b * NC * SP;   // channel 0 base (c1 at +SP)

    // Per-thread output coordinates (integers only — cheap to keep live).
    int rr = tid >> 3;
    int xi = (tid & 7) << 2;
    int yl = rr & 7, zl = rr >> 3;
    int y = Y0 + yl, z = Z0 + zl, x = X0 + xi;
    int go = (z * HH + y) * WW + x;          // geometric offset
    const float* fp = flow + b * 3 * SP + go;
    float* op = out + b * NC * SP + go;
    const int rx0 = X0 - 4, ry0 = Y0 - 3, rz0 = Z0 - 3;

    // ================= Phase 1: channel 0 =================
    stage_channel(sb, X0, Y0, Z0, tid, sbuf);

    {
        // Flow loads (in flight across staging drain). Plain cached loads —
        // phase 2 re-reads them from L2.
        v4f dxv = *reinterpret_cast<const v4f*>(fp);
        v4f dyv = *reinterpret_cast<const v4f*>(fp + SP);
        v4f dzv = *reinterpret_cast<const v4f*>(fp + 2 * SP);

        __syncthreads();                 // drains vmcnt: LDS staged
        if (edge) {                      // block-uniform branch
            fix_edge(sbuf, tid, left);
            __syncthreads();
        }

        float a[4];
        #pragma unroll
        for (int j = 0; j < 4; ++j) {
            float dx = dxv[j], dy = dyv[j], dz = dzv[j];
            bool inH = (dx >= -4.0f) & (dx < 4.0f) &
                       (dy >= -3.0f) & (dy < 4.0f) &
                       (dz >= -3.0f) & (dz < 4.0f);
            if (inH) {
                float lx = (float)(xi + j + 4) + dx;
                float ly = (float)(yl + 3) + dy;
                float lz = (float)(zl + 3) + dz;
                a[j] = sample_lds(sbuf, lx, ly, lz, rx0, ry0, rz0);
            } else {
                // ~0.3% of samples: outside staged halo (or NaN).
                a[j] = sample_global1(sb, x + j, y, z, dx, dy, dz);
            }
        }
        v4f o = {a[0], a[1], a[2], a[3]};
        st4_nt(op, o);
    }
    __syncthreads();   // all waves done reading c0 from LDS

    // ================= Phase 2: channel 1 =================
    stage_channel(sb + SP, X0, Y0, Z0, tid, sbuf);

    {
        v4f dxv = *reinterpret_cast<const v4f*>(fp);
        v4f dyv = *reinterpret_cast<const v4f*>(fp + SP);
        v4f dzv = *reinterpret_cast<const v4f*>(fp + 2 * SP);

        __syncthreads();
        if (edge) {
            fix_edge(sbuf, tid, left);
            __syncthreads();
        }

        float a[4];
        #pragma unroll
        for (int j = 0; j < 4; ++j) {
            float dx = dxv[j], dy = dyv[j], dz = dzv[j];
            bool inH = (dx >= -4.0f) & (dx < 4.0f) &
                       (dy >= -3.0f) & (dy < 4.0f) &
                       (dz >= -3.0f) & (dz < 4.0f);
            if (inH) {
                float lx = (float)(xi + j + 4) + dx;
                float ly = (float)(yl + 3) + dy;
                float lz = (float)(zl + 3) + dz;
                a[j] = sample_lds(sbuf, lx, ly, lz, rx0, ry0, rz0);
            } else {
                a[j] = sample_global1(sb + SP, x + j, y, z, dx, dy, dz);
            }
        }
        v4f o = {a[0], a[1], a[2], a[3]};
        st4_nt(op + SP, o);
    }
}

extern "C" void kernel_launch(void* const* d_in, const int* in_sizes, int n_in,
                              void* d_out, int out_size, void* d_ws, size_t ws_size,
                              hipStream_t stream) {
    const float* src  = (const float*)d_in[0];
    const float* flow = (const float*)d_in[1];
    float* out = (float*)d_out;

    st_warp_kernel<<<NTILES, 512, 0, stream>>>(src, flow, out);
}

// Round 5
// 269.185 us; speedup vs baseline: 1.3022x; 1.0523x over previous
//
#include <hip/hip_runtime.h>

// SIZE = (D,H,W) = (160,192,160), B=2, C=2.
#define DD 160
#define HH 192
#define WW 160
#define SP (DD * HH * WW)
#define NB 2
#define NC 2

// Tile per block and staged (edge-replicated) region.
// Persistent blocks, 512 threads, 4 samples/thread, channel-split phases
// with DOUBLE-BUFFERED LDS: stage of next phase is issued before compute of
// the current phase, so the vmcnt drain at each __syncthreads lands after a
// full compute phase of overlap (T3 minimum-2-phase pipeline).
#define TX 32
#define TY 8
#define TZ 8
#define RXW 40                 // x: [X0-4, X0+35]  supports dx in [-4,4)
#define RYH 15                 // y: [Y0-3, Y0+11]  supports dy in [-3,4)
#define RZD 15                 // z: [Z0-3, Z0+11]  supports dz in [-3,4)
#define REGC (RZD * RYH * RXW) // 9000 voxels; 36,000 B per buffer
#define NCHUNK (REGC / 4)      // 2250 4-voxel chunks
#define NITER 5                // ceil(2250/512)

#define NTX 5
#define NTY 24
#define NTZ 20
#define NTILES (NTX * NTY * NTZ * NB)   // 4800 tiles
#define TPX (NTILES / 8)                // 600 tiles per XCD
#define NBLK 512                        // persistent: 2 blocks/CU

typedef float v2f __attribute__((ext_vector_type(2)));
typedef float v4f __attribute__((ext_vector_type(4)));

typedef const void __attribute__((address_space(1)))* gas_ptr;
typedef void __attribute__((address_space(3)))* las_ptr;

__device__ __forceinline__ v4f ld4_nt(const float* p) {
    return __builtin_nontemporal_load(reinterpret_cast<const v4f*>(p));
}
__device__ __forceinline__ void st4_nt(float* p, v4f v) {
    __builtin_nontemporal_store(v, reinterpret_cast<v4f*>(p));
}
__device__ __forceinline__ v2f ld2g(const float* p) {
    return *reinterpret_cast<const v2f*>(p);
}

// Rare fallback: displacement outside staged halo — full global trilinear,
// single channel. (~0.3% of samples.)
__device__ __forceinline__ float sample_global1(
    const float* __restrict__ s,
    int x, int y, int z, float dx, float dy, float dz)
{
    float sx = (float)x + dx, sy = (float)y + dy, sz = (float)z + dz;
    float xf = floorf(sx), yf = floorf(sy), zf = floorf(sz);
    float fx = sx - xf, fy = sy - yf, fz = sz - zf;
    int x0 = (int)xf, y0 = (int)yf, z0 = (int)zf;
    int x1 = x0 + 1, y1 = y0 + 1, z1 = z0 + 1;

    float wx0 = (x0 >= 0 && x0 < WW) ? (1.0f - fx) : 0.0f;
    float wx1 = (x1 >= 0 && x1 < WW) ? fx : 0.0f;
    float wy0 = (y0 >= 0 && y0 < HH) ? (1.0f - fy) : 0.0f;
    float wy1 = (y1 >= 0 && y1 < HH) ? fy : 0.0f;
    float wz0 = (z0 >= 0 && z0 < DD) ? (1.0f - fz) : 0.0f;
    float wz1 = (z1 >= 0 && z1 < DD) ? fz : 0.0f;

    int p  = min(max(x0, 0), WW - 2);
    int i0 = min(max(x0, 0), WW - 1) - p;
    int i1 = min(max(x1, 0), WW - 1) - p;
    int cy0 = min(max(y0, 0), HH - 1), cy1 = min(max(y1, 0), HH - 1);
    int cz0 = min(max(z0, 0), DD - 1), cz1 = min(max(z1, 0), DD - 1);

    int o00 = (cz0 * HH + cy0) * WW + p;
    int o01 = (cz0 * HH + cy1) * WW + p;
    int o10 = (cz1 * HH + cy0) * WW + p;
    int o11 = (cz1 * HH + cy1) * WW + p;

    v2f c00 = ld2g(s + o00);
    v2f c01 = ld2g(s + o01);
    v2f c10 = ld2g(s + o10);
    v2f c11 = ld2g(s + o11);

    #define PICK(v, i) ((i) ? (v).y : (v).x)
    float r;
    r  = (wz0 * wy0) * (wx0 * PICK(c00, i0) + wx1 * PICK(c00, i1));
    r += (wz0 * wy1) * (wx0 * PICK(c01, i0) + wx1 * PICK(c01, i1));
    r += (wz1 * wy0) * (wx0 * PICK(c10, i0) + wx1 * PICK(c10, i1));
    r += (wz1 * wy1) * (wx0 * PICK(c11, i0) + wx1 * PICK(c11, i1));
    #undef PICK
    return r;
}

// Stage one channel into one LDS buffer via direct global->LDS DMA.
// Chunk c lands at sbuf[4c] (layout identity: region idx of chunk c == 4c),
// so within a wave the LDS destination is base + lane*16 — exactly the
// global_load_lds constraint.
//
// EDGE NOTE (why no post-fix is needed): chunks are either fully in-volume
// (staged correctly) or fully out-of-volume (x: only lxc=0 at X0=0 /
// lxc=9 at X0=128; y/z: clamped rows). Out-of-volume region cells are ONLY
// ever read with zero weight — the wx/wy/wz masks in sample_lds test the
// *volume* coordinate, and padding_mode='zeros' means such cells never
// contribute. The clamp below exists solely to keep addresses in-bounds;
// the (finite, real-data) garbage it stages is provably multiplied by 0.
__device__ __forceinline__ void stage_channel(
    const float* __restrict__ cb, int X0, int Y0, int Z0, int tid, float* sbuf)
{
    #pragma unroll
    for (int i = 0; i < NITER; ++i) {
        int c = tid + i * 512;
        if (i < NITER - 1 || c < NCHUNK) {
            int lz  = c / 150;  int r2 = c - lz * 150;   // 150 = RYH*RXW/4
            int ly  = r2 / 10;  int lxc = r2 - ly * 10;  // 10 = RXW/4
            int mz = min(max(Z0 - 3 + lz, 0), DD - 1);
            int my = min(max(Y0 - 3 + ly, 0), HH - 1);
            int mx = min(max(X0 - 4 + lxc * 4, 0), WW - 4);  // 16B-aligned
            const float* g = cb + (mz * HH + my) * WW + mx;
            __builtin_amdgcn_global_load_lds(
                (gas_ptr)g, (las_ptr)(sbuf + 4 * c), 16, 0, 0);
        }
    }
}

// Trilinear sample of the single-channel staged region.
__device__ __forceinline__ float sample_lds(
    const float* __restrict__ sbuf,
    float lx, float ly, float lz, int rx0, int ry0, int rz0)
{
    float xf = floorf(lx), yf = floorf(ly), zf = floorf(lz);
    float fx = lx - xf, fy = ly - yf, fz = lz - zf;
    int ix = (int)xf, iy = (int)yf, iz = (int)zf;

    // Zero-weight masks vs volume bounds (values come edge-clamped from
    // LDS — out-of-volume cells are zero-weighted here, see EDGE NOTE).
    int vx0 = ix + rx0, vy0 = iy + ry0, vz0 = iz + rz0;
    float wx0 = (vx0 >= 0  && vx0 < WW)     ? (1.0f - fx) : 0.0f;
    float wx1 = (vx0 >= -1 && vx0 < WW - 1) ? fx          : 0.0f;
    float wy0 = (vy0 >= 0  && vy0 < HH)     ? (1.0f - fy) : 0.0f;
    float wy1 = (vy0 >= -1 && vy0 < HH - 1) ? fy          : 0.0f;
    float wz0 = (vz0 >= 0  && vz0 < DD)     ? (1.0f - fz) : 0.0f;
    float wz1 = (vz0 >= -1 && vz0 < DD - 1) ? fz          : 0.0f;

    const float* pB = sbuf + (iz * RYH + iy) * RXW + ix;
    // Adjacent x0/x1 pairs -> ds_read2_b32.
    float A00 = pB[0],        B00 = pB[1];
    float A01 = pB[RXW],      B01 = pB[RXW + 1];
    const float* pC = pB + RYH * RXW;
    float A10 = pC[0],        B10 = pC[1];
    float A11 = pC[RXW],      B11 = pC[RXW + 1];

    float c00 = wx0 * A00 + wx1 * B00;
    float c01 = wx0 * A01 + wx1 * B01;
    float c10 = wx0 * A10 + wx1 * B10;
    float c11 = wx0 * A11 + wx1 * B11;
    float m0  = wy0 * c00 + wy1 * c01;
    float m1  = wy0 * c10 + wy1 * c11;
    return wz0 * m0 + wz1 * m1;
}

struct Geo {
    int X0, Y0, Z0;
    int x, y, z;          // this thread's global coords (x = first of 4)
    const float* sb;      // src channel-0 base for this batch
    const float* fp;      // flow pointer for this thread
    float* op;            // out pointer (channel 0) for this thread
};

__device__ __forceinline__ Geo decode_tile(
    int tl, const float* src, const float* flow, float* out,
    int xi, int yl, int zl)
{
    Geo g;
    int tx = tl % NTX;  int t2 = tl / NTX;
    int ty = t2 % NTY;  int t3 = t2 / NTY;
    int tz = t3 % NTZ;  int b  = t3 / NTZ;
    g.X0 = tx * TX; g.Y0 = ty * TY; g.Z0 = tz * TZ;
    g.x = g.X0 + xi; g.y = g.Y0 + yl; g.z = g.Z0 + zl;
    int go = (g.z * HH + g.y) * WW + g.x;
    g.sb = src + b * NC * SP;
    g.fp = flow + b * 3 * SP + go;
    g.op = out + b * NC * SP + go;
    return g;
}

// Compute 4 samples for one channel from LDS and store them.
__device__ __forceinline__ void compute_store(
    const float* __restrict__ sbuf, const Geo& g, int cofs,   // 0 or SP
    v4f dxv, v4f dyv, v4f dzv, int xi, int yl, int zl)
{
    const int rx0 = g.X0 - 4, ry0 = g.Y0 - 3, rz0 = g.Z0 - 3;
    float a[4];
    #pragma unroll
    for (int j = 0; j < 4; ++j) {
        float dx = dxv[j], dy = dyv[j], dz = dzv[j];
        bool inH = (dx >= -4.0f) & (dx < 4.0f) &
                   (dy >= -3.0f) & (dy < 4.0f) &
                   (dz >= -3.0f) & (dz < 4.0f);
        if (inH) {
            float lx = (float)(xi + j + 4) + dx;
            float ly = (float)(yl + 3) + dy;
            float lz = (float)(zl + 3) + dz;
            a[j] = sample_lds(sbuf, lx, ly, lz, rx0, ry0, rz0);
        } else {
            a[j] = sample_global1(g.sb + cofs, g.x + j, g.y, g.z, dx, dy, dz);
        }
    }
    v4f o = {a[0], a[1], a[2], a[3]};
    st4_nt(g.op + cofs, o);
}

// 2 blocks/CU (LDS-capped) -> 4 waves/SIMD -> VGPR budget 128: no spill.
__global__ __launch_bounds__(512, 4) void st_warp_kernel(
    const float* __restrict__ src,   // [B, C, D, H, W]
    const float* __restrict__ flow,  // [B, 3, D, H, W]
    float* __restrict__ out)         // [B, C, D, H, W]
{
    __shared__ float sA[REGC];   // channel-0 buffer
    __shared__ float sB[REGC];   // channel-1 buffer   (72,000 B total)

    int u    = blockIdx.x;
    int xcd  = u & 7;            // XCD-chunked tile ranges
    int slot = u >> 3;           // 0..63 within XCD
    int tid  = threadIdx.x;

    int rr = tid >> 3;
    int xi = (tid & 7) << 2;
    int yl = rr & 7, zl = rr >> 3;

    int nt = (TPX - slot + 63) >> 6;     // tiles for this block (9 or 10)
    int tl = xcd * TPX + slot;

    // ---- Prologue: stage tile 0 / c0, load its flow ----
    Geo g = decode_tile(tl, src, flow, out, xi, yl, zl);
    stage_channel(g.sb, g.X0, g.Y0, g.Z0, tid, sA);
    v4f dxv = ld4_nt(g.fp);
    v4f dyv = ld4_nt(g.fp + SP);
    v4f dzv = ld4_nt(g.fp + 2 * SP);

    for (int t = 0; t < nt; ++t) {
        __syncthreads();     // drains vmcnt: sA(c0,t) staged; sB free

        // Issue c1 staging, then compute c0 — stage hides under compute.
        stage_channel(g.sb + SP, g.X0, g.Y0, g.Z0, tid, sB);
        compute_store(sA, g, 0, dxv, dyv, dzv, xi, yl, zl);

        __syncthreads();     // drains vmcnt: sB(c1,t) staged; sA free

        // Issue next tile's c0 staging + flow loads, then compute c1.
        bool more = (t + 1 < nt);          // block-uniform
        Geo gn = g;
        v4f nxv = dxv, nyv = dyv, nzv = dzv;
        if (more) {
            gn = decode_tile(tl + ((t + 1) << 6), src, flow, out, xi, yl, zl);
            stage_channel(gn.sb, gn.X0, gn.Y0, gn.Z0, tid, sA);
            nxv = ld4_nt(gn.fp);
            nyv = ld4_nt(gn.fp + SP);
            nzv = ld4_nt(gn.fp + 2 * SP);
        }
        compute_store(sB, g, SP, dxv, dyv, dzv, xi, yl, zl);

        g = gn; dxv = nxv; dyv = nyv; dzv = nzv;
    }
}

extern "C" void kernel_launch(void* const* d_in, const int* in_sizes, int n_in,
                              void* d_out, int out_size, void* d_ws, size_t ws_size,
                              hipStream_t stream) {
    const float* src  = (const float*)d_in[0];
    const float* flow = (const float*)d_in[1];
    float* out = (float*)d_out;

    st_warp_kernel<<<NBLK, 512, 0, stream>>>(src, flow, out);
}